// Round 7
// baseline (105.563 us; speedup 1.0000x reference)
//
#include <hip/hip_runtime.h>

#define F     128   // in/out features
#define PAD   64    // padded adjacency slots per node
#define CHUNK 2048  // edges per XCD-replication group (R7: 8192->2048, 4x bucket blocks)

typedef short short8 __attribute__((ext_vector_type(8)));
typedef float f32x4v __attribute__((ext_vector_type(4)));

__device__ __forceinline__ ushort f2bf(float f) {
    uint b = __float_as_uint(f);
    uint r = (b + 0x7fffu + ((b >> 16) & 1u)) >> 16;
    return (ushort)r;
}
__device__ __forceinline__ float bflo(uint v) { return __uint_as_float(v << 16); }
__device__ __forceinline__ float bfhi(uint v) { return __uint_as_float(v & 0xffff0000u); }

// ---------------- K1: prep = zero cnt + W -> bf16^T ----------------

__global__ __launch_bounds__(256) void prep(
    const float* __restrict__ w, ushort* __restrict__ wt,
    int* __restrict__ cnt, int n)
{
    int i = blockIdx.x * 256 + threadIdx.x;
    if (i < n) cnt[i] = 0;
    if (blockIdx.x == 0) {
        for (int idx = threadIdx.x; idx < F * 32; idx += 256) {   // 4096 float4s of W
            int k = idx >> 5, c4 = idx & 31;
            float4 v = *reinterpret_cast<const float4*>(&w[k * F + c4 * 4]);
            wt[(c4 * 4 + 0) * F + k] = f2bf(v.x);
            wt[(c4 * 4 + 1) * F + k] = f2bf(v.y);
            wt[(c4 * 4 + 2) * F + k] = f2bf(v.z);
            wt[(c4 * 4 + 3) * F + k] = f2bf(v.w);
        }
    }
}

// ---------------- K2: hybrid (NO LDS) ----------------
// Bucket blocks [0,nbB): 8 blocks per edge-chunk, one per XCD (blockIdx&7);
//   each keeps only dst in its XCD's node range -> cnt atomics + padded writes stay L2-local.
// GEMM blocks [nbB,..): tile 64r x 128c, K=128; wave = 32r x 64c; A from global x
//   (fp32->bf16 in regs), B from global wt. D layout (m89): row=(l>>4)*4+rr, col=(l&15).

__global__ __launch_bounds__(256) void hybrid(
    const int* __restrict__ src, const int* __restrict__ dst, int ne,
    int* __restrict__ cnt, ushort* __restrict__ padded, int nbB,
    const float* __restrict__ x, const ushort* __restrict__ wt,
    ushort* __restrict__ g, int n)
{
    if (blockIdx.x < nbB) {
        const int grp = blockIdx.x >> 3;
        const int xcd = blockIdx.x & 7;
        const int sh  = (n + 7) >> 3;
        const int dlo = xcd * sh;
        const int dhi = (dlo + sh) < n ? (dlo + sh) : n;
        const int base = grp * CHUNK;
        const int lim  = (base + CHUNK) < ne ? (base + CHUNK) : ne;
        for (int e0 = base + threadIdx.x * 4; e0 < lim; e0 += 1024) {
            if (e0 + 3 < lim) {
                int4 s4 = *reinterpret_cast<const int4*>(&src[e0]);
                int4 d4 = *reinterpret_cast<const int4*>(&dst[e0]);
                if (d4.x >= dlo && d4.x < dhi) {
                    int p = atomicAdd(&cnt[d4.x], 1);
                    if (p < PAD) padded[(size_t)d4.x * PAD + p] = (ushort)s4.x;
                }
                if (d4.y >= dlo && d4.y < dhi) {
                    int p = atomicAdd(&cnt[d4.y], 1);
                    if (p < PAD) padded[(size_t)d4.y * PAD + p] = (ushort)s4.y;
                }
                if (d4.z >= dlo && d4.z < dhi) {
                    int p = atomicAdd(&cnt[d4.z], 1);
                    if (p < PAD) padded[(size_t)d4.z * PAD + p] = (ushort)s4.z;
                }
                if (d4.w >= dlo && d4.w < dhi) {
                    int p = atomicAdd(&cnt[d4.w], 1);
                    if (p < PAD) padded[(size_t)d4.w * PAD + p] = (ushort)s4.w;
                }
            } else {
                for (int e = e0; e < lim; ++e) {
                    int d = dst[e];
                    if (d >= dlo && d < dhi) {
                        int p = atomicAdd(&cnt[d], 1);
                        if (p < PAD) padded[(size_t)d * PAD + p] = (ushort)src[e];
                    }
                }
            }
        }
        return;
    }

    const int gb   = blockIdx.x - nbB;
    const int t    = threadIdx.x;
    const int lane = t & 63;
    const int wv   = t >> 6;
    const int wr   = wv >> 1, wc = wv & 1;
    const int l15  = lane & 15, kg = lane >> 4;
    const int row0 = gb * 64 + wr * 32;
    const int col0 = wc * 64;

    f32x4v acc[2][4];
    #pragma unroll
    for (int rt = 0; rt < 2; ++rt)
        #pragma unroll
        for (int ct = 0; ct < 4; ++ct)
            acc[rt][ct] = (f32x4v){0.f, 0.f, 0.f, 0.f};

    #pragma unroll
    for (int kt = 0; kt < 4; ++kt) {
        const int k0 = kt * 32 + kg * 8;
        short8 a[2];
        #pragma unroll
        for (int rt = 0; rt < 2; ++rt) {
            int row = row0 + rt * 16 + l15;
            row = row < n ? row : n - 1;                       // clamp (stores guarded)
            float4 p0 = *reinterpret_cast<const float4*>(&x[(size_t)row * F + k0]);
            float4 p1 = *reinterpret_cast<const float4*>(&x[(size_t)row * F + k0 + 4]);
            ushort u[8] = {f2bf(p0.x), f2bf(p0.y), f2bf(p0.z), f2bf(p0.w),
                           f2bf(p1.x), f2bf(p1.y), f2bf(p1.z), f2bf(p1.w)};
            a[rt] = *reinterpret_cast<short8*>(u);
        }
        short8 b[4];
        #pragma unroll
        for (int ct = 0; ct < 4; ++ct) {
            int col = col0 + ct * 16 + l15;
            b[ct] = *reinterpret_cast<const short8*>(&wt[col * F + k0]);
        }
        #pragma unroll
        for (int rt = 0; rt < 2; ++rt)
            #pragma unroll
            for (int ct = 0; ct < 4; ++ct)
                acc[rt][ct] = __builtin_amdgcn_mfma_f32_16x16x32_bf16(
                    a[rt], b[ct], acc[rt][ct], 0, 0, 0);
    }

    #pragma unroll
    for (int rt = 0; rt < 2; ++rt) {
        int rbase = row0 + rt * 16 + kg * 4;
        #pragma unroll
        for (int ct = 0; ct < 4; ++ct) {
            int col = col0 + ct * 16 + l15;
            #pragma unroll
            for (int rr = 0; rr < 4; ++rr) {
                int row = rbase + rr;
                if (row < n)
                    g[(size_t)row * F + col] = f2bf(acc[rt][ct][rr]);
            }
        }
    }
}

// ---------------- K3: gather, one wave per dst node ----------------
// out[v] = dinv[v] * ( dinv[v]*h[v] + sum_s dinv[s]*h[s] ) + bias;  dinv = rsqrt(cnt+1)

__global__ __launch_bounds__(256) void gather_bf16(
    const int* __restrict__ cnt, const ushort* __restrict__ padded,
    const ushort* __restrict__ g, const float* __restrict__ bias,
    float* __restrict__ out, int n)
{
    int wid  = (blockIdx.x * 256 + threadIdx.x) >> 6;
    int lane = threadIdx.x & 63;
    if (wid >= n) return;
    wid = __builtin_amdgcn_readfirstlane(wid);   // wave-uniform -> scalar loads
    const int c = lane * 2;

    int   cv = cnt[wid];
    float dv = rsqrtf((float)cv + 1.0f);
    uint self = *reinterpret_cast<const uint*>(&g[(size_t)wid * F + c]);
    float ax = dv * bflo(self), ay = dv * bfhi(self);

    int m = cv < PAD ? cv : PAD;
    const ushort* pl = padded + (size_t)wid * PAD;

    int j = 0;
    for (; j + 4 <= m; j += 4) {
        int s0 = pl[j + 0], s1 = pl[j + 1], s2 = pl[j + 2], s3 = pl[j + 3];
        float d0 = rsqrtf((float)cnt[s0] + 1.0f);
        float d1 = rsqrtf((float)cnt[s1] + 1.0f);
        float d2 = rsqrtf((float)cnt[s2] + 1.0f);
        float d3 = rsqrtf((float)cnt[s3] + 1.0f);
        uint v0 = *reinterpret_cast<const uint*>(&g[(size_t)s0 * F + c]);
        uint v1 = *reinterpret_cast<const uint*>(&g[(size_t)s1 * F + c]);
        uint v2 = *reinterpret_cast<const uint*>(&g[(size_t)s2 * F + c]);
        uint v3 = *reinterpret_cast<const uint*>(&g[(size_t)s3 * F + c]);
        ax = fmaf(d0, bflo(v0), ax); ay = fmaf(d0, bfhi(v0), ay);
        ax = fmaf(d1, bflo(v1), ax); ay = fmaf(d1, bfhi(v1), ay);
        ax = fmaf(d2, bflo(v2), ax); ay = fmaf(d2, bfhi(v2), ay);
        ax = fmaf(d3, bflo(v3), ax); ay = fmaf(d3, bfhi(v3), ay);
    }
    for (; j < m; ++j) {
        int s = pl[j];
        float ds = rsqrtf((float)cnt[s] + 1.0f);
        uint v = *reinterpret_cast<const uint*>(&g[(size_t)s * F + c]);
        ax = fmaf(ds, bflo(v), ax);
        ay = fmaf(ds, bfhi(v), ay);
    }

    float2 bb = *reinterpret_cast<const float2*>(&bias[c]);
    float2 o;
    o.x = fmaf(dv, ax, bb.x);
    o.y = fmaf(dv, ay, bb.y);
    *reinterpret_cast<float2*>(&out[(size_t)wid * F + c]) = o;
}

// ---------------- fallback path (fp32 atomics, minimal ws) ----------------

__global__ __launch_bounds__(256) void gemm_scale(
    const float* __restrict__ x, const float* __restrict__ w,
    const float* __restrict__ dinv, float* __restrict__ g, int n)
{
    __shared__ float sWl[F * F];
    __shared__ float sXl[8][F];
    for (int i = threadIdx.x; i < F * F; i += 256) sWl[i] = w[i];
    __syncthreads();
    const int r  = threadIdx.x >> 5;
    const int cg = threadIdx.x & 31;
    for (int row0 = blockIdx.x * 8; row0 < n; row0 += gridDim.x * 8) {
        {
            int t4 = threadIdx.x * 4;
            int rr = t4 >> 7, cc = t4 & (F - 1);
            if (row0 + rr < n) {
                float4 v = *reinterpret_cast<const float4*>(&x[(size_t)(row0 + rr) * F + cc]);
                *reinterpret_cast<float4*>(&sXl[rr][cc]) = v;
            }
        }
        __syncthreads();
        int row = row0 + r;
        if (row < n) {
            float4 acc = make_float4(0.f, 0.f, 0.f, 0.f);
            const float* xr = sXl[r];
            #pragma unroll 8
            for (int k = 0; k < F; ++k) {
                float  xv = xr[k];
                float4 wv = *reinterpret_cast<const float4*>(&sWl[k * F + cg * 4]);
                acc.x = fmaf(xv, wv.x, acc.x);
                acc.y = fmaf(xv, wv.y, acc.y);
                acc.z = fmaf(xv, wv.z, acc.z);
                acc.w = fmaf(xv, wv.w, acc.w);
            }
            float s = dinv[row];
            acc.x *= s; acc.y *= s; acc.z *= s; acc.w *= s;
            *reinterpret_cast<float4*>(&g[(size_t)row * F + cg * 4]) = acc;
        }
        __syncthreads();
    }
}

__global__ void init_degf(float* __restrict__ deg, int n) {
    int i = blockIdx.x * blockDim.x + threadIdx.x;
    if (i < n) deg[i] = 1.0f;
}
__global__ void count_degf(const int* __restrict__ dst, int ne, float* __restrict__ deg) {
    int e = blockIdx.x * blockDim.x + threadIdx.x;
    if (e < ne) atomicAdd(&deg[dst[e]], 1.0f);
}
__global__ void calc_dinvf(const float* __restrict__ deg, float* __restrict__ dinv, int n) {
    int i = blockIdx.x * blockDim.x + threadIdx.x;
    if (i < n) dinv[i] = rsqrtf(fmaxf(deg[i], 1e-12f));
}
__global__ __launch_bounds__(256) void scatter_edges(
    const int* __restrict__ src, const int* __restrict__ dst, int ne,
    const float* __restrict__ g, float* __restrict__ out)
{
    int gid  = (blockIdx.x * blockDim.x + threadIdx.x) >> 5;
    int lane = threadIdx.x & 31;
    if (gid >= ne) return;
    int s = src[gid], d = dst[gid];
    float4 v = *reinterpret_cast<const float4*>(&g[(size_t)s * F + lane * 4]);
    float* op = &out[(size_t)d * F + lane * 4];
    atomicAdd(op + 0, v.x);
    atomicAdd(op + 1, v.y);
    atomicAdd(op + 2, v.z);
    atomicAdd(op + 3, v.w);
}
__global__ __launch_bounds__(256) void finalize(
    float* __restrict__ out, const float* __restrict__ g,
    const float* __restrict__ dinv, const float* __restrict__ bias, int n)
{
    int i = blockIdx.x * blockDim.x + threadIdx.x;
    if (i >= n * 32) return;
    int row = i >> 5, c4 = i & 31;
    float  s = dinv[row];
    float4 o = *reinterpret_cast<float4*>(&out[(size_t)i * 4]);
    float4 gg = *reinterpret_cast<const float4*>(&g[(size_t)i * 4]);
    float4 b = *reinterpret_cast<const float4*>(&bias[c4 * 4]);
    o.x = fmaf(s, o.x + gg.x, b.x);
    o.y = fmaf(s, o.y + gg.y, b.y);
    o.z = fmaf(s, o.z + gg.z, b.z);
    o.w = fmaf(s, o.w + gg.w, b.w);
    *reinterpret_cast<float4*>(&out[(size_t)i * 4]) = o;
}

// ---------------- launcher ----------------

extern "C" void kernel_launch(void* const* d_in, const int* in_sizes, int n_in,
                              void* d_out, int out_size, void* d_ws, size_t ws_size,
                              hipStream_t stream) {
    const float* x     = (const float*)d_in[0];
    const int*   index = (const int*)d_in[1];
    const float* w     = (const float*)d_in[2];
    const float* bias  = (const float*)d_in[3];
    float*       out   = (float*)d_out;

    int n  = in_sizes[0] / F;   // 50000
    int ne = in_sizes[1] / 2;   // 625000
    const int* src = index;
    const int* dst = index + ne;

    // workspace layout (bytes)
    size_t b_cnt    = 0;
    size_t b_wt     = (b_cnt + (size_t)n * 4 + 15) & ~(size_t)15;
    size_t b_padded = (b_wt + (size_t)F * F * 2 + 15) & ~(size_t)15;
    size_t b_g      = (b_padded + (size_t)n * PAD * 2 + 15) & ~(size_t)15;
    size_t need     = b_g + (size_t)n * F * 2;

    char* wsb = (char*)d_ws;
    int*    cnt    = (int*)(wsb + b_cnt);
    ushort* wt     = (ushort*)(wsb + b_wt);
    ushort* padded = (ushort*)(wsb + b_padded);
    ushort* g      = (ushort*)(wsb + b_g);

    int nb  = (n + 255) / 256;                            // 196
    int nbB = ((ne + CHUNK - 1) / CHUNK) * 8;             // 2448 bucket blocks
    int nbG = (n + 63) / 64;                              // 782 gemm blocks

    if (ws_size >= need && n <= 65535) {
        prep<<<nb, 256, 0, stream>>>(w, wt, cnt, n);
        hybrid<<<nbB + nbG, 256, 0, stream>>>(src, dst, ne, cnt, padded, nbB, x, wt, g, n);
        int gb = (int)(((long long)n * 64 + 255) / 256);
        gather_bf16<<<gb, 256, 0, stream>>>(cnt, padded, g, bias, out, n);
    } else {
        // fallback: fp32 atomic path
        float* degf  = (float*)wsb;
        float* dinvf = (float*)wsb + n;
        float* gf    = (float*)wsb + 2 * n;
        int nbE = (ne + 255) / 256;
        hipMemsetAsync(d_out, 0, (size_t)out_size * sizeof(float), stream);
        init_degf<<<nb, 256, 0, stream>>>(degf, n);
        count_degf<<<nbE, 256, 0, stream>>>(dst, ne, degf);
        calc_dinvf<<<nb, 256, 0, stream>>>(degf, dinvf, n);
        gemm_scale<<<(n + 7) / 8, 256, 0, stream>>>(x, w, dinvf, gf, n);
        int sc_blocks = (int)(((long long)ne * 32 + 255) / 256);
        scatter_edges<<<sc_blocks, 256, 0, stream>>>(src, dst, ne, gf, out);
        finalize<<<(n * 32 + 255) / 256, 256, 0, stream>>>(out, gf, dinvf, bias, n);
    }
}

// Round 8
// 100.004 us; speedup vs baseline: 1.0556x; 1.0556x over previous
//
#include <hip/hip_runtime.h>

#define F   128  // in/out features
#define PAD 64   // padded adjacency slots per node

typedef short short8 __attribute__((ext_vector_type(8)));
typedef float f32x4v __attribute__((ext_vector_type(4)));

__device__ __forceinline__ ushort f2bf(float f) {
    uint b = __float_as_uint(f);
    uint r = (b + 0x7fffu + ((b >> 16) & 1u)) >> 16;
    return (ushort)r;
}
__device__ __forceinline__ float bflo(uint v) { return __uint_as_float(v << 16); }
__device__ __forceinline__ float bfhi(uint v) { return __uint_as_float(v & 0xffff0000u); }

// ---------------- K1: hybrid (NO LDS) ----------------
// Bucket blocks [0,nbB): 1 edge/thread, one-pass padded-CSR build.
// GEMM blocks [nbB,..): tile 64r x 128c, K=128; wave = 32r x 64c; A from global x
//   (fp32->bf16 in regs), B from global w fp32 (strided, L1/L2-hot).
//   D layout (m89): row=(l>>4)*4+rr, col=(l&15).

__global__ __launch_bounds__(256) void hybrid(
    const int* __restrict__ src, const int* __restrict__ dst, int ne,
    int* __restrict__ cnt, ushort* __restrict__ padded, int nbB,
    const float* __restrict__ x, const float* __restrict__ w,
    ushort* __restrict__ g, int n)
{
    if (blockIdx.x < nbB) {
        int e = blockIdx.x * 256 + threadIdx.x;
        if (e < ne) {
            int s = src[e], d = dst[e];
            int p = atomicAdd(&cnt[d], 1);
            if (p < PAD) padded[(size_t)d * PAD + p] = (ushort)s;
        }
        return;
    }

    const int gb   = blockIdx.x - nbB;
    const int t    = threadIdx.x;
    const int lane = t & 63;
    const int wv   = t >> 6;
    const int wr   = wv >> 1, wc = wv & 1;
    const int l15  = lane & 15, kg = lane >> 4;
    const int row0 = gb * 64 + wr * 32;
    const int col0 = wc * 64;

    f32x4v acc[2][4];
    #pragma unroll
    for (int rt = 0; rt < 2; ++rt)
        #pragma unroll
        for (int ct = 0; ct < 4; ++ct)
            acc[rt][ct] = (f32x4v){0.f, 0.f, 0.f, 0.f};

    #pragma unroll
    for (int kt = 0; kt < 4; ++kt) {
        const int k0 = kt * 32 + kg * 8;
        short8 a[2];
        #pragma unroll
        for (int rt = 0; rt < 2; ++rt) {
            int row = row0 + rt * 16 + l15;
            row = row < n ? row : n - 1;                       // clamp (stores guarded)
            float4 p0 = *reinterpret_cast<const float4*>(&x[(size_t)row * F + k0]);
            float4 p1 = *reinterpret_cast<const float4*>(&x[(size_t)row * F + k0 + 4]);
            ushort u[8] = {f2bf(p0.x), f2bf(p0.y), f2bf(p0.z), f2bf(p0.w),
                           f2bf(p1.x), f2bf(p1.y), f2bf(p1.z), f2bf(p1.w)};
            a[rt] = *reinterpret_cast<short8*>(u);
        }
        short8 b[4];
        #pragma unroll
        for (int ct = 0; ct < 4; ++ct) {
            int col = col0 + ct * 16 + l15;
            ushort u[8];
            #pragma unroll
            for (int j = 0; j < 8; ++j)
                u[j] = f2bf(w[(size_t)(k0 + j) * F + col]);    // W[k][col], stride-F
            b[ct] = *reinterpret_cast<short8*>(u);
        }
        #pragma unroll
        for (int rt = 0; rt < 2; ++rt)
            #pragma unroll
            for (int ct = 0; ct < 4; ++ct)
                acc[rt][ct] = __builtin_amdgcn_mfma_f32_16x16x32_bf16(
                    a[rt], b[ct], acc[rt][ct], 0, 0, 0);
    }

    #pragma unroll
    for (int rt = 0; rt < 2; ++rt) {
        int rbase = row0 + rt * 16 + kg * 4;
        #pragma unroll
        for (int ct = 0; ct < 4; ++ct) {
            int col = col0 + ct * 16 + l15;
            #pragma unroll
            for (int rr = 0; rr < 4; ++rr) {
                int row = rbase + rr;
                if (row < n)
                    g[(size_t)row * F + col] = f2bf(acc[rt][ct][rr]);
            }
        }
    }
}

// ---------------- K2: gather, one wave per dst node ----------------
// out[v] = dinv[v] * ( dinv[v]*h[v] + sum_s dinv[s]*h[s] ) + bias;  dinv = rsqrt(cnt+1)

__global__ __launch_bounds__(256) void gather_bf16(
    const int* __restrict__ cnt, const ushort* __restrict__ padded,
    const ushort* __restrict__ g, const float* __restrict__ bias,
    float* __restrict__ out, int n)
{
    int wid  = (blockIdx.x * 256 + threadIdx.x) >> 6;
    int lane = threadIdx.x & 63;
    if (wid >= n) return;
    wid = __builtin_amdgcn_readfirstlane(wid);   // wave-uniform -> scalar loads
    const int c = lane * 2;

    int   cv = cnt[wid];
    float dv = rsqrtf((float)cv + 1.0f);
    uint self = *reinterpret_cast<const uint*>(&g[(size_t)wid * F + c]);
    float ax = dv * bflo(self), ay = dv * bfhi(self);

    int m = cv < PAD ? cv : PAD;
    const ushort* pl = padded + (size_t)wid * PAD;

    int j = 0;
    for (; j + 4 <= m; j += 4) {
        int s0 = pl[j + 0], s1 = pl[j + 1], s2 = pl[j + 2], s3 = pl[j + 3];
        float d0 = rsqrtf((float)cnt[s0] + 1.0f);
        float d1 = rsqrtf((float)cnt[s1] + 1.0f);
        float d2 = rsqrtf((float)cnt[s2] + 1.0f);
        float d3 = rsqrtf((float)cnt[s3] + 1.0f);
        uint v0 = *reinterpret_cast<const uint*>(&g[(size_t)s0 * F + c]);
        uint v1 = *reinterpret_cast<const uint*>(&g[(size_t)s1 * F + c]);
        uint v2 = *reinterpret_cast<const uint*>(&g[(size_t)s2 * F + c]);
        uint v3 = *reinterpret_cast<const uint*>(&g[(size_t)s3 * F + c]);
        ax = fmaf(d0, bflo(v0), ax); ay = fmaf(d0, bfhi(v0), ay);
        ax = fmaf(d1, bflo(v1), ax); ay = fmaf(d1, bfhi(v1), ay);
        ax = fmaf(d2, bflo(v2), ax); ay = fmaf(d2, bfhi(v2), ay);
        ax = fmaf(d3, bflo(v3), ax); ay = fmaf(d3, bfhi(v3), ay);
    }
    for (; j < m; ++j) {
        int s = pl[j];
        float ds = rsqrtf((float)cnt[s] + 1.0f);
        uint v = *reinterpret_cast<const uint*>(&g[(size_t)s * F + c]);
        ax = fmaf(ds, bflo(v), ax);
        ay = fmaf(ds, bfhi(v), ay);
    }

    float2 bb = *reinterpret_cast<const float2*>(&bias[c]);
    float2 o;
    o.x = fmaf(dv, ax, bb.x);
    o.y = fmaf(dv, ay, bb.y);
    *reinterpret_cast<float2*>(&out[(size_t)wid * F + c]) = o;
}

// ---------------- fallback path (fp32 atomics, minimal ws) ----------------

__global__ __launch_bounds__(256) void gemm_scale(
    const float* __restrict__ x, const float* __restrict__ w,
    const float* __restrict__ dinv, float* __restrict__ g, int n)
{
    __shared__ float sWl[F * F];
    __shared__ float sXl[8][F];
    for (int i = threadIdx.x; i < F * F; i += 256) sWl[i] = w[i];
    __syncthreads();
    const int r  = threadIdx.x >> 5;
    const int cg = threadIdx.x & 31;
    for (int row0 = blockIdx.x * 8; row0 < n; row0 += gridDim.x * 8) {
        {
            int t4 = threadIdx.x * 4;
            int rr = t4 >> 7, cc = t4 & (F - 1);
            if (row0 + rr < n) {
                float4 v = *reinterpret_cast<const float4*>(&x[(size_t)(row0 + rr) * F + cc]);
                *reinterpret_cast<float4*>(&sXl[rr][cc]) = v;
            }
        }
        __syncthreads();
        int row = row0 + r;
        if (row < n) {
            float4 acc = make_float4(0.f, 0.f, 0.f, 0.f);
            const float* xr = sXl[r];
            #pragma unroll 8
            for (int k = 0; k < F; ++k) {
                float  xv = xr[k];
                float4 wv = *reinterpret_cast<const float4*>(&sWl[k * F + cg * 4]);
                acc.x = fmaf(xv, wv.x, acc.x);
                acc.y = fmaf(xv, wv.y, acc.y);
                acc.z = fmaf(xv, wv.z, acc.z);
                acc.w = fmaf(xv, wv.w, acc.w);
            }
            float s = dinv[row];
            acc.x *= s; acc.y *= s; acc.z *= s; acc.w *= s;
            *reinterpret_cast<float4*>(&g[(size_t)row * F + cg * 4]) = acc;
        }
        __syncthreads();
    }
}

__global__ void init_degf(float* __restrict__ deg, int n) {
    int i = blockIdx.x * blockDim.x + threadIdx.x;
    if (i < n) deg[i] = 1.0f;
}
__global__ void count_degf(const int* __restrict__ dst, int ne, float* __restrict__ deg) {
    int e = blockIdx.x * blockDim.x + threadIdx.x;
    if (e < ne) atomicAdd(&deg[dst[e]], 1.0f);
}
__global__ void calc_dinvf(const float* __restrict__ deg, float* __restrict__ dinv, int n) {
    int i = blockIdx.x * blockDim.x + threadIdx.x;
    if (i < n) dinv[i] = rsqrtf(fmaxf(deg[i], 1e-12f));
}
__global__ __launch_bounds__(256) void scatter_edges(
    const int* __restrict__ src, const int* __restrict__ dst, int ne,
    const float* __restrict__ g, float* __restrict__ out)
{
    int gid  = (blockIdx.x * blockDim.x + threadIdx.x) >> 5;
    int lane = threadIdx.x & 31;
    if (gid >= ne) return;
    int s = src[gid], d = dst[gid];
    float4 v = *reinterpret_cast<const float4*>(&g[(size_t)s * F + lane * 4]);
    float* op = &out[(size_t)d * F + lane * 4];
    atomicAdd(op + 0, v.x);
    atomicAdd(op + 1, v.y);
    atomicAdd(op + 2, v.z);
    atomicAdd(op + 3, v.w);
}
__global__ __launch_bounds__(256) void finalize(
    float* __restrict__ out, const float* __restrict__ g,
    const float* __restrict__ dinv, const float* __restrict__ bias, int n)
{
    int i = blockIdx.x * blockDim.x + threadIdx.x;
    if (i >= n * 32) return;
    int row = i >> 5, c4 = i & 31;
    float  s = dinv[row];
    float4 o = *reinterpret_cast<float4*>(&out[(size_t)i * 4]);
    float4 gg = *reinterpret_cast<const float4*>(&g[(size_t)i * 4]);
    float4 b = *reinterpret_cast<const float4*>(&bias[c4 * 4]);
    o.x = fmaf(s, o.x + gg.x, b.x);
    o.y = fmaf(s, o.y + gg.y, b.y);
    o.z = fmaf(s, o.z + gg.z, b.z);
    o.w = fmaf(s, o.w + gg.w, b.w);
    *reinterpret_cast<float4*>(&out[(size_t)i * 4]) = o;
}

// ---------------- launcher ----------------

extern "C" void kernel_launch(void* const* d_in, const int* in_sizes, int n_in,
                              void* d_out, int out_size, void* d_ws, size_t ws_size,
                              hipStream_t stream) {
    const float* x     = (const float*)d_in[0];
    const int*   index = (const int*)d_in[1];
    const float* w     = (const float*)d_in[2];
    const float* bias  = (const float*)d_in[3];
    float*       out   = (float*)d_out;

    int n  = in_sizes[0] / F;   // 50000
    int ne = in_sizes[1] / 2;   // 625000
    const int* src = index;
    const int* dst = index + ne;

    // workspace layout (bytes)
    size_t b_cnt    = 0;
    size_t b_padded = (b_cnt + (size_t)n * 4 + 15) & ~(size_t)15;
    size_t b_g      = (b_padded + (size_t)n * PAD * 2 + 15) & ~(size_t)15;
    size_t need     = b_g + (size_t)n * F * 2;

    char* wsb = (char*)d_ws;
    int*    cnt    = (int*)(wsb + b_cnt);
    ushort* padded = (ushort*)(wsb + b_padded);
    ushort* g      = (ushort*)(wsb + b_g);

    int nbB = (ne + 255) / 256;   // 2442 bucket blocks (1 edge/thread)
    int nbG = (n + 63) / 64;      // 782 gemm blocks

    if (ws_size >= need && n <= 65535) {
        hipMemsetAsync(cnt, 0, (size_t)n * 4, stream);
        hybrid<<<nbB + nbG, 256, 0, stream>>>(src, dst, ne, cnt, padded, nbB, x, w, g, n);
        int gb = (int)(((long long)n * 64 + 255) / 256);
        gather_bf16<<<gb, 256, 0, stream>>>(cnt, padded, g, bias, out, n);
    } else {
        // fallback: fp32 atomic path
        float* degf  = (float*)wsb;
        float* dinvf = (float*)wsb + n;
        float* gf    = (float*)wsb + 2 * n;
        int nb  = (n + 255) / 256;
        int nbE = (ne + 255) / 256;
        hipMemsetAsync(d_out, 0, (size_t)out_size * sizeof(float), stream);
        init_degf<<<nb, 256, 0, stream>>>(degf, n);
        count_degf<<<nbE, 256, 0, stream>>>(dst, ne, degf);
        calc_dinvf<<<nb, 256, 0, stream>>>(degf, dinvf, n);
        gemm_scale<<<(n + 7) / 8, 256, 0, stream>>>(x, w, dinvf, gf, n);
        int sc_blocks = (int)(((long long)ne * 32 + 255) / 256);
        scatter_edges<<<sc_blocks, 256, 0, stream>>>(src, dst, ne, gf, out);
        finalize<<<(n * 32 + 255) / 256, 256, 0, stream>>>(out, gf, dinvf, bias, n);
    }
}

// Round 9
// 94.359 us; speedup vs baseline: 1.1187x; 1.0598x over previous
//
#include <hip/hip_runtime.h>

#define F   128  // in/out features
#define PAD 64   // padded adjacency slots per node (column-major: slot p at padded[p*n+d])

typedef short short8 __attribute__((ext_vector_type(8)));
typedef float f32x4v __attribute__((ext_vector_type(4)));

__device__ __forceinline__ ushort f2bf(float f) {
    uint b = __float_as_uint(f);
    uint r = (b + 0x7fffu + ((b >> 16) & 1u)) >> 16;
    return (ushort)r;
}
__device__ __forceinline__ float bflo(uint v) { return __uint_as_float(v << 16); }
__device__ __forceinline__ float bfhi(uint v) { return __uint_as_float(v & 0xffff0000u); }

// ---------------- K1: hybrid (NO LDS) ----------------
// Bucket blocks [0,nbB): 1 edge/thread, one-pass padded-CSR build, COLUMN-MAJOR slots:
//   padded[p*n + d] — active slot regions (p < ~25) total ~2.5MB -> L2-resident,
//   densely dirtied lines -> write-back ~= payload (R8 row-major: 47MB for 2.5MB payload).
// GEMM blocks [nbB,..): tile 64r x 128c, K=128; wave = 32r x 64c; A from global x
//   (fp32->bf16 in regs), B from global w fp32 (strided, L1/L2-hot).
//   D layout (m89): row=(l>>4)*4+rr, col=(l&15).

__global__ __launch_bounds__(256) void hybrid(
    const int* __restrict__ src, const int* __restrict__ dst, int ne,
    int* __restrict__ cnt, ushort* __restrict__ padded, int nbB,
    const float* __restrict__ x, const float* __restrict__ w,
    ushort* __restrict__ g, int n)
{
    if (blockIdx.x < nbB) {
        int e = blockIdx.x * 256 + threadIdx.x;
        if (e < ne) {
            int s = src[e], d = dst[e];
            int p = atomicAdd(&cnt[d], 1);
            if (p < PAD) padded[(size_t)p * n + d] = (ushort)s;   // column-major
        }
        return;
    }

    const int gb   = blockIdx.x - nbB;
    const int t    = threadIdx.x;
    const int lane = t & 63;
    const int wv   = t >> 6;
    const int wr   = wv >> 1, wc = wv & 1;
    const int l15  = lane & 15, kg = lane >> 4;
    const int row0 = gb * 64 + wr * 32;
    const int col0 = wc * 64;

    f32x4v acc[2][4];
    #pragma unroll
    for (int rt = 0; rt < 2; ++rt)
        #pragma unroll
        for (int ct = 0; ct < 4; ++ct)
            acc[rt][ct] = (f32x4v){0.f, 0.f, 0.f, 0.f};

    #pragma unroll
    for (int kt = 0; kt < 4; ++kt) {
        const int k0 = kt * 32 + kg * 8;
        short8 a[2];
        #pragma unroll
        for (int rt = 0; rt < 2; ++rt) {
            int row = row0 + rt * 16 + l15;
            row = row < n ? row : n - 1;                       // clamp (stores guarded)
            float4 p0 = *reinterpret_cast<const float4*>(&x[(size_t)row * F + k0]);
            float4 p1 = *reinterpret_cast<const float4*>(&x[(size_t)row * F + k0 + 4]);
            ushort u[8] = {f2bf(p0.x), f2bf(p0.y), f2bf(p0.z), f2bf(p0.w),
                           f2bf(p1.x), f2bf(p1.y), f2bf(p1.z), f2bf(p1.w)};
            a[rt] = *reinterpret_cast<short8*>(u);
        }
        short8 b[4];
        #pragma unroll
        for (int ct = 0; ct < 4; ++ct) {
            int col = col0 + ct * 16 + l15;
            ushort u[8];
            #pragma unroll
            for (int j = 0; j < 8; ++j)
                u[j] = f2bf(w[(size_t)(k0 + j) * F + col]);    // W[k][col], stride-F
            b[ct] = *reinterpret_cast<short8*>(u);
        }
        #pragma unroll
        for (int rt = 0; rt < 2; ++rt)
            #pragma unroll
            for (int ct = 0; ct < 4; ++ct)
                acc[rt][ct] = __builtin_amdgcn_mfma_f32_16x16x32_bf16(
                    a[rt], b[ct], acc[rt][ct], 0, 0, 0);
    }

    #pragma unroll
    for (int rt = 0; rt < 2; ++rt) {
        int rbase = row0 + rt * 16 + kg * 4;
        #pragma unroll
        for (int ct = 0; ct < 4; ++ct) {
            int col = col0 + ct * 16 + l15;
            #pragma unroll
            for (int rr = 0; rr < 4; ++rr) {
                int row = rbase + rr;
                if (row < n)
                    g[(size_t)row * F + col] = f2bf(acc[rt][ct][rr]);
            }
        }
    }
}

// ---------------- K2: gather, one wave per dst node ----------------
// out[v] = dinv[v] * ( dinv[v]*h[v] + sum_s dinv[s]*h[s] ) + bias;  dinv = rsqrt(cnt+1)

__global__ __launch_bounds__(256) void gather_bf16(
    const int* __restrict__ cnt, const ushort* __restrict__ padded,
    const ushort* __restrict__ g, const float* __restrict__ bias,
    float* __restrict__ out, int n)
{
    int wid  = (blockIdx.x * 256 + threadIdx.x) >> 6;
    int lane = threadIdx.x & 63;
    if (wid >= n) return;
    wid = __builtin_amdgcn_readfirstlane(wid);   // wave-uniform -> scalar loads
    const int c = lane * 2;

    int   cv = cnt[wid];
    float dv = rsqrtf((float)cv + 1.0f);
    uint self = *reinterpret_cast<const uint*>(&g[(size_t)wid * F + c]);
    float ax = dv * bflo(self), ay = dv * bfhi(self);

    int m = cv < PAD ? cv : PAD;

    int j = 0;
    for (; j + 4 <= m; j += 4) {
        int s0 = padded[(size_t)(j + 0) * n + wid];
        int s1 = padded[(size_t)(j + 1) * n + wid];
        int s2 = padded[(size_t)(j + 2) * n + wid];
        int s3 = padded[(size_t)(j + 3) * n + wid];
        float d0 = rsqrtf((float)cnt[s0] + 1.0f);
        float d1 = rsqrtf((float)cnt[s1] + 1.0f);
        float d2 = rsqrtf((float)cnt[s2] + 1.0f);
        float d3 = rsqrtf((float)cnt[s3] + 1.0f);
        uint v0 = *reinterpret_cast<const uint*>(&g[(size_t)s0 * F + c]);
        uint v1 = *reinterpret_cast<const uint*>(&g[(size_t)s1 * F + c]);
        uint v2 = *reinterpret_cast<const uint*>(&g[(size_t)s2 * F + c]);
        uint v3 = *reinterpret_cast<const uint*>(&g[(size_t)s3 * F + c]);
        ax = fmaf(d0, bflo(v0), ax); ay = fmaf(d0, bfhi(v0), ay);
        ax = fmaf(d1, bflo(v1), ax); ay = fmaf(d1, bfhi(v1), ay);
        ax = fmaf(d2, bflo(v2), ax); ay = fmaf(d2, bfhi(v2), ay);
        ax = fmaf(d3, bflo(v3), ax); ay = fmaf(d3, bfhi(v3), ay);
    }
    for (; j < m; ++j) {
        int s = padded[(size_t)j * n + wid];
        float ds = rsqrtf((float)cnt[s] + 1.0f);
        uint v = *reinterpret_cast<const uint*>(&g[(size_t)s * F + c]);
        ax = fmaf(ds, bflo(v), ax);
        ay = fmaf(ds, bfhi(v), ay);
    }

    float2 bb = *reinterpret_cast<const float2*>(&bias[c]);
    float2 o;
    o.x = fmaf(dv, ax, bb.x);
    o.y = fmaf(dv, ay, bb.y);
    *reinterpret_cast<float2*>(&out[(size_t)wid * F + c]) = o;
}

// ---------------- fallback path (fp32 atomics, minimal ws) ----------------

__global__ __launch_bounds__(256) void gemm_scale(
    const float* __restrict__ x, const float* __restrict__ w,
    const float* __restrict__ dinv, float* __restrict__ g, int n)
{
    __shared__ float sWl[F * F];
    __shared__ float sXl[8][F];
    for (int i = threadIdx.x; i < F * F; i += 256) sWl[i] = w[i];
    __syncthreads();
    const int r  = threadIdx.x >> 5;
    const int cg = threadIdx.x & 31;
    for (int row0 = blockIdx.x * 8; row0 < n; row0 += gridDim.x * 8) {
        {
            int t4 = threadIdx.x * 4;
            int rr = t4 >> 7, cc = t4 & (F - 1);
            if (row0 + rr < n) {
                float4 v = *reinterpret_cast<const float4*>(&x[(size_t)(row0 + rr) * F + cc]);
                *reinterpret_cast<float4*>(&sXl[rr][cc]) = v;
            }
        }
        __syncthreads();
        int row = row0 + r;
        if (row < n) {
            float4 acc = make_float4(0.f, 0.f, 0.f, 0.f);
            const float* xr = sXl[r];
            #pragma unroll 8
            for (int k = 0; k < F; ++k) {
                float  xv = xr[k];
                float4 wv = *reinterpret_cast<const float4*>(&sWl[k * F + cg * 4]);
                acc.x = fmaf(xv, wv.x, acc.x);
                acc.y = fmaf(xv, wv.y, acc.y);
                acc.z = fmaf(xv, wv.z, acc.z);
                acc.w = fmaf(xv, wv.w, acc.w);
            }
            float s = dinv[row];
            acc.x *= s; acc.y *= s; acc.z *= s; acc.w *= s;
            *reinterpret_cast<float4*>(&g[(size_t)row * F + cg * 4]) = acc;
        }
        __syncthreads();
    }
}

__global__ void init_degf(float* __restrict__ deg, int n) {
    int i = blockIdx.x * blockDim.x + threadIdx.x;
    if (i < n) deg[i] = 1.0f;
}
__global__ void count_degf(const int* __restrict__ dst, int ne, float* __restrict__ deg) {
    int e = blockIdx.x * blockDim.x + threadIdx.x;
    if (e < ne) atomicAdd(&deg[dst[e]], 1.0f);
}
__global__ void calc_dinvf(const float* __restrict__ deg, float* __restrict__ dinv, int n) {
    int i = blockIdx.x * blockDim.x + threadIdx.x;
    if (i < n) dinv[i] = rsqrtf(fmaxf(deg[i], 1e-12f));
}
__global__ __launch_bounds__(256) void scatter_edges(
    const int* __restrict__ src, const int* __restrict__ dst, int ne,
    const float* __restrict__ g, float* __restrict__ out)
{
    int gid  = (blockIdx.x * blockDim.x + threadIdx.x) >> 5;
    int lane = threadIdx.x & 31;
    if (gid >= ne) return;
    int s = src[gid], d = dst[gid];
    float4 v = *reinterpret_cast<const float4*>(&g[(size_t)s * F + lane * 4]);
    float* op = &out[(size_t)d * F + lane * 4];
    atomicAdd(op + 0, v.x);
    atomicAdd(op + 1, v.y);
    atomicAdd(op + 2, v.z);
    atomicAdd(op + 3, v.w);
}
__global__ __launch_bounds__(256) void finalize(
    float* __restrict__ out, const float* __restrict__ g,
    const float* __restrict__ dinv, const float* __restrict__ bias, int n)
{
    int i = blockIdx.x * blockDim.x + threadIdx.x;
    if (i >= n * 32) return;
    int row = i >> 5, c4 = i & 31;
    float  s = dinv[row];
    float4 o = *reinterpret_cast<float4*>(&out[(size_t)i * 4]);
    float4 gg = *reinterpret_cast<const float4*>(&g[(size_t)i * 4]);
    float4 b = *reinterpret_cast<const float4*>(&bias[c4 * 4]);
    o.x = fmaf(s, o.x + gg.x, b.x);
    o.y = fmaf(s, o.y + gg.y, b.y);
    o.z = fmaf(s, o.z + gg.z, b.z);
    o.w = fmaf(s, o.w + gg.w, b.w);
    *reinterpret_cast<float4*>(&out[(size_t)i * 4]) = o;
}

// ---------------- launcher ----------------

extern "C" void kernel_launch(void* const* d_in, const int* in_sizes, int n_in,
                              void* d_out, int out_size, void* d_ws, size_t ws_size,
                              hipStream_t stream) {
    const float* x     = (const float*)d_in[0];
    const int*   index = (const int*)d_in[1];
    const float* w     = (const float*)d_in[2];
    const float* bias  = (const float*)d_in[3];
    float*       out   = (float*)d_out;

    int n  = in_sizes[0] / F;   // 50000
    int ne = in_sizes[1] / 2;   // 625000
    const int* src = index;
    const int* dst = index + ne;

    // workspace layout (bytes)
    size_t b_cnt    = 0;
    size_t b_padded = (b_cnt + (size_t)n * 4 + 15) & ~(size_t)15;
    size_t b_g      = (b_padded + (size_t)n * PAD * 2 + 15) & ~(size_t)15;
    size_t need     = b_g + (size_t)n * F * 2;

    char* wsb = (char*)d_ws;
    int*    cnt    = (int*)(wsb + b_cnt);
    ushort* padded = (ushort*)(wsb + b_padded);
    ushort* g      = (ushort*)(wsb + b_g);

    int nbB = (ne + 255) / 256;   // 2442 bucket blocks (1 edge/thread)
    int nbG = (n + 63) / 64;      // 782 gemm blocks

    if (ws_size >= need && n <= 65535) {
        hipMemsetAsync(cnt, 0, (size_t)n * 4, stream);
        hybrid<<<nbB + nbG, 256, 0, stream>>>(src, dst, ne, cnt, padded, nbB, x, w, g, n);
        int gb = (int)(((long long)n * 64 + 255) / 256);
        gather_bf16<<<gb, 256, 0, stream>>>(cnt, padded, g, bias, out, n);
    } else {
        // fallback: fp32 atomic path
        float* degf  = (float*)wsb;
        float* dinvf = (float*)wsb + n;
        float* gf    = (float*)wsb + 2 * n;
        int nb  = (n + 255) / 256;
        int nbE = (ne + 255) / 256;
        hipMemsetAsync(d_out, 0, (size_t)out_size * sizeof(float), stream);
        init_degf<<<nb, 256, 0, stream>>>(degf, n);
        count_degf<<<nbE, 256, 0, stream>>>(dst, ne, degf);
        calc_dinvf<<<nb, 256, 0, stream>>>(degf, dinvf, n);
        gemm_scale<<<(n + 7) / 8, 256, 0, stream>>>(x, w, dinvf, gf, n);
        int sc_blocks = (int)(((long long)ne * 32 + 255) / 256);
        scatter_edges<<<sc_blocks, 256, 0, stream>>>(src, dst, ne, gf, out);
        finalize<<<(n * 32 + 255) / 256, 256, 0, stream>>>(out, gf, dinvf, bias, n);
    }
}